// Round 12
// baseline (25405.510 us; speedup 1.0000x reference)
//
#include <hip/hip_runtime.h>
#include <stdint.h>

// FPS: B=8, C=3, N=131072, S=2048.
// R10 structure (proven 3754us): 64 blocks x 64 threads (1 wave) per batch,
// 512 blocks cooperative, batch = blockIdx % 8 (co-XCD heuristic), contiguous
// ownership (thread owns 32 consecutive indices; slot order == block order ==
// index order -> ties = lowest lane/slot = first occurrence == jnp.argmax).
// Flat symmetric sync: every wave polls all 64 slots (lane i watches slot i,
// ONE load in flight -- R11's 4-deep pipeline ADDED contention, regressed),
// fmax+ballot reduce, XCD-L2 volatile fast path + agent-scope CAP fallback
// (correct under any block->XCD placement; no hang, graceful degrade).
// Speculative per-lane candidate-coord gather hides the winner gather under
// the slot-reduce butterfly; winner coords arrive via 3 shfl.
// R12 single change vs R10: EARLY POST -- the first lane achieving the wave
// max posts directly (its own bi IS the wave winner by contiguous-ownership
// tie-break), removing ffs+shfl from the pre-post critical path; widx/mypk
// extraction moves after the store (needed only for the rare CAP fallback).
// Exact __f*_rn arithmetic, (dx*dx+dy*dy)+dz*dz order: trajectory bitwise-
// identical to reference (absmax 0 in R1-R11).

#define BATCHES 8
#define KBLK    64                  // blocks per batch == slots == lanes
#define TPB     64
#define NPTS    131072
#define CHUNK   (NPTS / KBLK)       // 2048 points per block
#define PPT     (CHUNK / TPB)       // 32 points per thread
#define CAP     64                  // fast-poll spins before agent fallback

__global__ __launch_bounds__(TPB, 1) void fps_kernel(
    const float* __restrict__ pts, float* __restrict__ out,
    unsigned long long* __restrict__ ws, int S)
{
    const int gb   = blockIdx.x;            // 0..511
    const int b    = gb & (BATCHES - 1);    // batch (co-XCD heuristic)
    const int blk  = gb >> 3;               // 0..63 within batch
    const int lane = threadIdx.x;           // 0..63

    const float* X = pts + (size_t)(b * 3 + 0) * NPTS;
    const float* Y = pts + (size_t)(b * 3 + 1) * NPTS;
    const float* Z = pts + (size_t)(b * 3 + 2) * NPTS;
    float* outb = out + (size_t)b * 3 * S;

    // Contiguous ownership: [base2, base2 + PPT)
    const int base2 = blk * CHUNK + lane * PPT;

    float px[PPT], py[PPT], pz[PPT], md[PPT];
#pragma unroll
    for (int q = 0; q < PPT / 4; ++q) {
        float4 vx = *reinterpret_cast<const float4*>(&X[base2 + 4 * q]);
        float4 vy = *reinterpret_cast<const float4*>(&Y[base2 + 4 * q]);
        float4 vz = *reinterpret_cast<const float4*>(&Z[base2 + 4 * q]);
        px[4*q+0] = vx.x; px[4*q+1] = vx.y; px[4*q+2] = vx.z; px[4*q+3] = vx.w;
        py[4*q+0] = vy.x; py[4*q+1] = vy.y; py[4*q+2] = vy.z; py[4*q+3] = vy.w;
        pz[4*q+0] = vz.x; pz[4*q+1] = vz.y; pz[4*q+2] = vz.z; pz[4*q+3] = vz.w;
    }
#pragma unroll
    for (int k = 0; k < PPT; ++k) md[k] = 1e10f;

    // Slot arrays: [parity][batch][KBLK]; agent (IC) backstop + fast (L2).
    unsigned long long* const agnP[2] = {
        ws + (size_t)b * KBLK,
        ws + (size_t)(BATCHES + b) * KBLK };
    volatile unsigned long long* const fstP[2] = {
        (volatile unsigned long long*)(ws + (size_t)(2 * BATCHES + b) * KBLK),
        (volatile unsigned long long*)(ws + (size_t)(3 * BATCHES + b) * KBLK) };

    // Round 0 selection is index 0 (reference).
    float cx = X[0], cy = Y[0], cz = Z[0];
    if (blk == 0 && lane == 0) {
        outb[0]             = cx;
        outb[(size_t)S]     = cy;
        outb[(size_t)2 * S] = cz;
    }

    for (int t = 0; t < S - 1; ++t) {
        // --- update min-dist + thread-local argmax (ascending k, strict >) ---
        float bv = -1.0f;
        int   bk = 0;
#pragma unroll
        for (int k = 0; k < PPT; ++k) {
            float dx = __fsub_rn(px[k], cx);
            float dy = __fsub_rn(py[k], cy);
            float dz = __fsub_rn(pz[k], cz);
            // numpy/jax order: (dx*dx + dy*dy) + dz*dz, no FMA contraction
            float d  = __fadd_rn(__fadd_rn(__fmul_rn(dx, dx), __fmul_rn(dy, dy)),
                                 __fmul_rn(dz, dz));
            float m  = fminf(md[k], d);
            md[k] = m;
            if (m > bv) { bv = m; bk = k; }
        }
        const int bi = base2 + bk;

        // --- wave reduce: fmax butterfly; tie -> lowest lane == lowest idx ---
        float v = bv;
#pragma unroll
        for (int off = 32; off >= 1; off >>= 1)
            v = fmaxf(v, __shfl_xor(v, off));
        unsigned long long eq = __ballot(bv == v);

        const unsigned long long tagv = (unsigned long long)(t + 1); // 1..2047

        volatile unsigned long long* fst = fstP[t & 1];
        unsigned long long*          agn = agnP[t & 1];

        // --- EARLY POST: first lane achieving v posts its own (v, bi) --
        //     by contiguous ownership this IS the wave's first-occurrence
        //     winner; no ffs/shfl before the store ---
        const unsigned long long below = (lane == 63) ? ~0ull
                                       : ((1ull << (lane + 1)) - 1) >> 1;
        if (bv == v && (eq & below) == 0)
            fst[blk] = ((unsigned long long)__float_as_uint(v) << 32) |
                       ((unsigned long long)(unsigned)(0x1FFFF - bi) << 12) |
                       tagv;

        // (for CAP fallback only -- off the critical path)
        int flane0 = __ffsll(eq) - 1;
        int widx   = __shfl(bi, flane0);
        const unsigned long long mypk =
            ((unsigned long long)__float_as_uint(v) << 32) |
            ((unsigned long long)(unsigned)(0x1FFFF - widx) << 12) | tagv;

        // --- poll: lane i watches slot i; agent fallback after CAP spins ---
        unsigned long long g;
        {
            int  spins  = 0;
            bool capped = false;
            for (;;) {
                unsigned long long gf = fst[lane];
                bool ok = ((gf & 0xFFFull) == tagv);
                if (capped && !ok) {
                    unsigned long long ga = __hip_atomic_load(&agn[lane],
                        __ATOMIC_RELAXED, __HIP_MEMORY_SCOPE_AGENT);
                    if ((ga & 0xFFFull) == tagv) { gf = ga; ok = true; }
                }
                g = gf;
                if (__all((int)ok)) break;
                if (!capped && ++spins == CAP) {
                    capped = true;
                    if (lane == 0)
                        __hip_atomic_store(&agn[blk], mypk,
                            __ATOMIC_RELAXED, __HIP_MEMORY_SCOPE_AGENT);
                }
            }
        }

        // --- tail overlap: speculative per-lane gather of own-slot
        //     candidate's coords (L2-hit latency hides under butterfly) ---
        const int cand = 0x1FFFF - (int)((g >> 12) & 0x1FFFF);
        float gx = X[cand];
        float gy = Y[cand];
        float gz = Z[cand];

        // --- reduce 64 slot values: fmax butterfly + ballot; slot order ==
        //     block order == index order -> lowest lane = first occurrence ---
        float gv = __uint_as_float((unsigned)(g >> 32));
        float m2 = gv;
#pragma unroll
        for (int off = 32; off >= 1; off >>= 1)
            m2 = fmaxf(m2, __shfl_xor(m2, off));
        unsigned long long eq2 = __ballot(gv == m2);
        int fl = __ffsll(eq2) - 1;

        // --- winner's coords via shfl (no serial scalar gather) ---
        cx = __shfl(gx, fl);
        cy = __shfl(gy, fl);
        cz = __shfl(gz, fl);
        if (blk == 0 && lane == 0) {
            outb[(size_t)(t + 1)]         = cx;
            outb[(size_t)S + (t + 1)]     = cy;
            outb[(size_t)2 * S + (t + 1)] = cz;
        }
    }
}

extern "C" void kernel_launch(void* const* d_in, const int* in_sizes, int n_in,
                              void* d_out, int out_size, void* d_ws, size_t ws_size,
                              hipStream_t stream) {
    const float* pts = (const float*)d_in[0];
    float* out = (float*)d_out;
    unsigned long long* ws = (unsigned long long*)d_ws;
    int S = out_size / (BATCHES * 3);   // 2048

    // Zero all 4 slot arrays (2 parities x {agent, fast}) every replay.
    hipMemsetAsync(d_ws, 0,
                   (size_t)4 * BATCHES * KBLK * sizeof(unsigned long long),
                   stream);

    void* args[] = { (void*)&pts, (void*)&out, (void*)&ws, (void*)&S };
    hipLaunchCooperativeKernel((const void*)fps_kernel,
                               dim3(BATCHES * KBLK), dim3(TPB),
                               args, 0, stream);
}

// Round 13
// 3760.722 us; speedup vs baseline: 6.7555x; 6.7555x over previous
//
#include <hip/hip_runtime.h>
#include <stdint.h>

// FPS: B=8, C=3, N=131072, S=2048.
// R10 PROVEN KERNEL (3754us, tight replays) restored verbatim after R11
// (4-deep poll, +contention) and R12 (early divergent post -> chronic CAP
// fallback storm) both regressed. Structure:
// 64 blocks x 64 threads (1 wave) per batch, 512 blocks cooperative,
// batch = blockIdx % 8 (co-XCD heuristic), contiguous ownership (thread owns
// 32 consecutive indices; slot order == block order == index order -> ties =
// lowest lane/slot = first occurrence == jnp.argmax).
// Flat symmetric sync: lane-0 posts the block winner to an XCD-L2 volatile
// slot (value|invidx|tag in one aligned 8B atom); every wave polls all 64
// slots (lane i watches slot i, ONE load in flight); agent-scope CAP
// fallback keeps correctness independent of block->XCD placement (no hang,
// graceful degrade). Speculative per-lane candidate-coord gather hides the
// winner gather under the slot-reduce butterfly; winner coords via 3 shfl.
// Exact __f*_rn arithmetic, (dx*dx+dy*dy)+dz*dz order: trajectory bitwise-
// identical to reference (absmax 0 in R1-R12).

#define BATCHES 8
#define KBLK    64                  // blocks per batch == slots == lanes
#define TPB     64
#define NPTS    131072
#define CHUNK   (NPTS / KBLK)       // 2048 points per block
#define PPT     (CHUNK / TPB)       // 32 points per thread
#define CAP     64                  // fast-poll spins before agent fallback

__global__ __launch_bounds__(TPB, 1) void fps_kernel(
    const float* __restrict__ pts, float* __restrict__ out,
    unsigned long long* __restrict__ ws, int S)
{
    const int gb   = blockIdx.x;            // 0..511
    const int b    = gb & (BATCHES - 1);    // batch (co-XCD heuristic)
    const int blk  = gb >> 3;               // 0..63 within batch
    const int lane = threadIdx.x;           // 0..63

    const float* X = pts + (size_t)(b * 3 + 0) * NPTS;
    const float* Y = pts + (size_t)(b * 3 + 1) * NPTS;
    const float* Z = pts + (size_t)(b * 3 + 2) * NPTS;
    float* outb = out + (size_t)b * 3 * S;

    // Contiguous ownership: [base2, base2 + PPT)
    const int base2 = blk * CHUNK + lane * PPT;

    float px[PPT], py[PPT], pz[PPT], md[PPT];
#pragma unroll
    for (int q = 0; q < PPT / 4; ++q) {
        float4 vx = *reinterpret_cast<const float4*>(&X[base2 + 4 * q]);
        float4 vy = *reinterpret_cast<const float4*>(&Y[base2 + 4 * q]);
        float4 vz = *reinterpret_cast<const float4*>(&Z[base2 + 4 * q]);
        px[4*q+0] = vx.x; px[4*q+1] = vx.y; px[4*q+2] = vx.z; px[4*q+3] = vx.w;
        py[4*q+0] = vy.x; py[4*q+1] = vy.y; py[4*q+2] = vy.z; py[4*q+3] = vy.w;
        pz[4*q+0] = vz.x; pz[4*q+1] = vz.y; pz[4*q+2] = vz.z; pz[4*q+3] = vz.w;
    }
#pragma unroll
    for (int k = 0; k < PPT; ++k) md[k] = 1e10f;

    // Slot arrays: [parity][batch][KBLK]; agent (IC) backstop + fast (L2).
    unsigned long long* const agnP[2] = {
        ws + (size_t)b * KBLK,
        ws + (size_t)(BATCHES + b) * KBLK };
    volatile unsigned long long* const fstP[2] = {
        (volatile unsigned long long*)(ws + (size_t)(2 * BATCHES + b) * KBLK),
        (volatile unsigned long long*)(ws + (size_t)(3 * BATCHES + b) * KBLK) };

    // Round 0 selection is index 0 (reference).
    float cx = X[0], cy = Y[0], cz = Z[0];
    if (blk == 0 && lane == 0) {
        outb[0]             = cx;
        outb[(size_t)S]     = cy;
        outb[(size_t)2 * S] = cz;
    }

    for (int t = 0; t < S - 1; ++t) {
        // --- update min-dist + thread-local argmax (ascending k, strict >) ---
        float bv = -1.0f;
        int   bk = 0;
#pragma unroll
        for (int k = 0; k < PPT; ++k) {
            float dx = __fsub_rn(px[k], cx);
            float dy = __fsub_rn(py[k], cy);
            float dz = __fsub_rn(pz[k], cz);
            // numpy/jax order: (dx*dx + dy*dy) + dz*dz, no FMA contraction
            float d  = __fadd_rn(__fadd_rn(__fmul_rn(dx, dx), __fmul_rn(dy, dy)),
                                 __fmul_rn(dz, dz));
            float m  = fminf(md[k], d);
            md[k] = m;
            if (m > bv) { bv = m; bk = k; }
        }
        const int bi = base2 + bk;

        // --- wave reduce: fmax butterfly; tie -> lowest lane == lowest idx ---
        float v = bv;
#pragma unroll
        for (int off = 32; off >= 1; off >>= 1)
            v = fmaxf(v, __shfl_xor(v, off));
        unsigned long long eq = __ballot(bv == v);
        int   flane = __ffsll(eq) - 1;
        int   widx  = __shfl(bi, flane);

        const unsigned long long tagv = (unsigned long long)(t + 1); // 1..2047
        const unsigned long long mypk =
            ((unsigned long long)__float_as_uint(v) << 32) |
            ((unsigned long long)(unsigned)(0x1FFFF - widx) << 12) | tagv;

        volatile unsigned long long* fst = fstP[t & 1];
        unsigned long long*          agn = agnP[t & 1];

        // --- post (fast, XCD-L2) ---
        if (lane == 0) fst[blk] = mypk;

        // --- poll: lane i watches slot i; agent fallback after CAP spins ---
        unsigned long long g;
        {
            int  spins  = 0;
            bool capped = false;
            for (;;) {
                unsigned long long gf = fst[lane];
                bool ok = ((gf & 0xFFFull) == tagv);
                if (capped && !ok) {
                    unsigned long long ga = __hip_atomic_load(&agn[lane],
                        __ATOMIC_RELAXED, __HIP_MEMORY_SCOPE_AGENT);
                    if ((ga & 0xFFFull) == tagv) { gf = ga; ok = true; }
                }
                g = gf;
                if (__all((int)ok)) break;
                if (!capped && ++spins == CAP) {
                    capped = true;
                    if (lane == 0)
                        __hip_atomic_store(&agn[blk], mypk,
                            __ATOMIC_RELAXED, __HIP_MEMORY_SCOPE_AGENT);
                }
            }
        }

        // --- tail overlap: speculative per-lane gather of own-slot
        //     candidate's coords (L2-hit latency hides under butterfly) ---
        const int cand = 0x1FFFF - (int)((g >> 12) & 0x1FFFF);
        float gx = X[cand];
        float gy = Y[cand];
        float gz = Z[cand];

        // --- reduce 64 slot values: fmax butterfly + ballot; slot order ==
        //     block order == index order -> lowest lane = first occurrence ---
        float gv = __uint_as_float((unsigned)(g >> 32));
        float m2 = gv;
#pragma unroll
        for (int off = 32; off >= 1; off >>= 1)
            m2 = fmaxf(m2, __shfl_xor(m2, off));
        unsigned long long eq2 = __ballot(gv == m2);
        int fl = __ffsll(eq2) - 1;

        // --- winner's coords via shfl (no serial scalar gather) ---
        cx = __shfl(gx, fl);
        cy = __shfl(gy, fl);
        cz = __shfl(gz, fl);
        if (blk == 0 && lane == 0) {
            outb[(size_t)(t + 1)]         = cx;
            outb[(size_t)S + (t + 1)]     = cy;
            outb[(size_t)2 * S + (t + 1)] = cz;
        }
    }
}

extern "C" void kernel_launch(void* const* d_in, const int* in_sizes, int n_in,
                              void* d_out, int out_size, void* d_ws, size_t ws_size,
                              hipStream_t stream) {
    const float* pts = (const float*)d_in[0];
    float* out = (float*)d_out;
    unsigned long long* ws = (unsigned long long*)d_ws;
    int S = out_size / (BATCHES * 3);   // 2048

    // Zero all 4 slot arrays (2 parities x {agent, fast}) every replay.
    hipMemsetAsync(d_ws, 0,
                   (size_t)4 * BATCHES * KBLK * sizeof(unsigned long long),
                   stream);

    void* args[] = { (void*)&pts, (void*)&out, (void*)&ws, (void*)&S };
    hipLaunchCooperativeKernel((const void*)fps_kernel,
                               dim3(BATCHES * KBLK), dim3(TPB),
                               args, 0, stream);
}